// Round 1
// baseline (1476.946 us; speedup 1.0000x reference)
//
#include <hip/hip_runtime.h>
#include <math.h>

#define NE 100000
#define NR 400
#define NT 1000000
#define B  32
#define DH 512

// ---------------------------------------------------------------------------
// prep: transpose e_s (B,NE) -> E0 (NE,B); zero E1; extract src/ans one-hot idx
// ---------------------------------------------------------------------------
__global__ __launch_bounds__(256) void prep_kernel(
    const float* __restrict__ e_s, const float* __restrict__ answers,
    float* __restrict__ E0, float* __restrict__ E1,
    int* __restrict__ SRC, int* __restrict__ ANS)
{
    int bid = blockIdx.x, tid = threadIdx.x;
    if (bid < NE / 32) {
        __shared__ float tile[32 * 33];
        int base_e = bid * 32;
        #pragma unroll
        for (int l = 0; l < 4; ++l) {
            int idx = l * 256 + tid;
            int br = idx >> 5, ec = idx & 31;               // read coalesced over ec
            tile[ec * 33 + br] = e_s[(size_t)br * NE + base_e + ec];
        }
        __syncthreads();
        #pragma unroll
        for (int l = 0; l < 4; ++l) {
            int idx = l * 256 + tid;
            int ew = idx >> 5, bw = idx & 31;               // write coalesced over bw
            E0[(size_t)(base_e + ew) * 32 + bw] = tile[ew * 33 + bw];
            E1[(size_t)base_e * 32 + idx] = 0.f;
        }
    } else {
        int b = bid - NE / 32;
        for (int i = tid; i < NE; i += 256) {
            if (e_s[(size_t)b * NE + i] > 0.5f)     SRC[b] = i;
            if (answers[(size_t)b * NE + i] > 0.5f) ANS[b] = i;
        }
    }
}

// ---------------------------------------------------------------------------
// stepA: per-batch-row b: cq = tanh(q_emb @ W_t^T + b_t); logits = cq @ rel_emb^T;
// softmax -> RD (NR,B transposed); argmax; gt (t==0); cond flags (t>=1); flag3 (t==2)
// ---------------------------------------------------------------------------
__global__ __launch_bounds__(256) void stepA_kernel(
    int t,
    const int* __restrict__ questions,
    const float* __restrict__ rel_emb,
    const float* __restrict__ step_W,
    const float* __restrict__ step_b,
    float* __restrict__ RD, float* __restrict__ GT,
    int* __restrict__ AM, int* __restrict__ COND, int* __restrict__ FLAG3)
{
    __shared__ float qe[DH];
    __shared__ float cq[DH];
    __shared__ float lg[NR];
    __shared__ float rv[256];
    __shared__ int   ri[256];
    int b = blockIdx.x, tid = threadIdx.x;
    int q = questions[b];

    for (int i = tid; i < DH; i += 256) qe[i] = rel_emb[(size_t)q * DH + i];
    __syncthreads();

    for (int i = tid; i < DH; i += 256) {
        const float4* w4 = (const float4*)(step_W + ((size_t)t * DH + i) * DH);
        float acc = step_b[t * DH + i];
        for (int j = 0; j < DH / 4; ++j) {
            float4 wv = w4[j];
            acc += wv.x * qe[4*j] + wv.y * qe[4*j+1] + wv.z * qe[4*j+2] + wv.w * qe[4*j+3];
        }
        cq[i] = tanhf(acc);
    }
    __syncthreads();

    float lmax = -1e30f; int lidx = 0;
    for (int r = tid; r < NR; r += 256) {
        const float4* re4 = (const float4*)(rel_emb + (size_t)r * DH);
        float acc = 0.f;
        for (int j = 0; j < DH / 4; ++j) {
            float4 wv = re4[j];
            acc += wv.x * cq[4*j] + wv.y * cq[4*j+1] + wv.z * cq[4*j+2] + wv.w * cq[4*j+3];
        }
        lg[r] = acc;
        if (acc > lmax) { lmax = acc; lidx = r; }   // first-max kept (ascending r)
    }
    rv[tid] = lmax; ri[tid] = lidx;
    __syncthreads();
    for (int s = 128; s > 0; s >>= 1) {
        if (tid < s) {
            float ov = rv[tid + s]; int oi = ri[tid + s];
            if (ov > rv[tid] || (ov == rv[tid] && oi < ri[tid])) { rv[tid] = ov; ri[tid] = oi; }
        }
        __syncthreads();
    }
    float mx = rv[0]; int amax = ri[0];
    __syncthreads();

    float lsum = 0.f;
    for (int r = tid; r < NR; r += 256) {
        float ex = expf(lg[r] - mx);
        lg[r] = ex;
        lsum += ex;
    }
    rv[tid] = lsum;
    __syncthreads();
    for (int s = 128; s > 0; s >>= 1) {
        if (tid < s) rv[tid] += rv[tid + s];
        __syncthreads();
    }
    float Z = rv[0];

    for (int r = tid; r < NR; r += 256) RD[r * B + b] = lg[r] / Z;

    if (tid == 0) {
        AM[t * B + b] = amax;
        if (t == 0) GT[b] = lg[q] / Z;
        if (t >= 1) {
            int ap = AM[(t - 1) * B + b];
            int d = ap - amax; if (d < 0) d = -d;
            int mn = ap < amax ? ap : amax;
            COND[(t - 1) * B + b] = (d == 1 && (mn % 2 == 0)) ? 1 : 0;
        }
        if (t == 2) {
            int a0 = AM[0 * B + b], a1 = AM[1 * B + b];
            int c = (a0 == 0) + (a1 == 0) + (amax == 0);
            FLAG3[b] = (c == 1) ? 1 : 0;
        }
    }
}

// ---------------------------------------------------------------------------
// follow: Eout[obj,b] += Ein[subj,b] * RD[rel,b]  (skip zero contributions)
// ---------------------------------------------------------------------------
__global__ __launch_bounds__(256) void follow_kernel(
    const float* __restrict__ Ein, float* __restrict__ Eout,
    const float* __restrict__ RD,
    const int* __restrict__ subj, const int* __restrict__ rel,
    const int* __restrict__ obj)
{
    long long gid = (long long)blockIdx.x * 256 + threadIdx.x;
    int trip = (int)(gid >> 5);
    int b = threadIdx.x & 31;
    if (trip < NT) {
        int s = subj[trip];
        float ev = Ein[(size_t)s * 32 + b];
        if (ev != 0.f) {
            int r = rel[trip];
            int o = obj[trip];
            float x = ev * RD[r * B + b];
            if (x != 0.f) unsafeAtomicAdd(&Eout[(size_t)o * 32 + b], x);
        }
    }
}

// ---------------------------------------------------------------------------
// post0 (t=0): subtract answers*gt at ans position, clamp; zero E2
// ---------------------------------------------------------------------------
__global__ __launch_bounds__(256) void post0_kernel(
    float* __restrict__ E1, float* __restrict__ E2,
    const int* __restrict__ ANS, const float* __restrict__ GT)
{
    int idx = blockIdx.x * 256 + threadIdx.x;
    int b = idx & 31, e = idx >> 5;
    float v = E1[idx];
    if (e == ANS[b]) v -= GT[b];
    if (v > 1.f) v = 1.f;           // x/x == 1.0f exactly for x>1
    E1[idx] = v;
    E2[idx] = 0.f;
}

// ---------------------------------------------------------------------------
// post1 (t=1): clamp; targeted zero where cond1 && e==src (e_s>0.9 mask);
// zero E0, P, S for later stages
// ---------------------------------------------------------------------------
__global__ __launch_bounds__(256) void post1_kernel(
    float* __restrict__ E2, float* __restrict__ E0,
    const int* __restrict__ COND1, const int* __restrict__ SRC,
    float* __restrict__ P, float* __restrict__ S)
{
    int idx = blockIdx.x * 256 + threadIdx.x;
    int b = idx & 31, e = idx >> 5;
    float v = E2[idx];
    if (v > 1.f) v = 1.f;
    if (COND1[b] && e == SRC[b]) v = 0.f;
    E2[idx] = v;
    E0[idx] = 0.f;
    if (idx < B * DH) P[idx] = 0.f;
    if (idx < B)      S[idx] = 0.f;
}

// ---------------------------------------------------------------------------
// post2 (t=2): clamp; zero where cond2 && P0>0.9; zero where flag3 && e==src;
// accumulate per-b row sums S
// ---------------------------------------------------------------------------
__global__ __launch_bounds__(256) void post2_kernel(
    float* __restrict__ E0, const float* __restrict__ E1,
    const int* __restrict__ COND2, const int* __restrict__ SRC,
    const int* __restrict__ FLAG3, float* __restrict__ S)
{
    __shared__ float sS[32];
    int tid = threadIdx.x;
    int idx = blockIdx.x * 256 + tid;
    int b = idx & 31, e = idx >> 5;
    if (tid < 32) sS[tid] = 0.f;
    __syncthreads();
    float v = E0[idx];
    if (v > 1.f) v = 1.f;
    if (COND2[b] && E1[idx] > 0.9f) v = 0.f;
    if (FLAG3[b] && e == SRC[b]) v = 0.f;
    E0[idx] = v;
    float vp = v + __shfl_xor(v, 32, 64);   // lane and lane+32 share b
    if ((tid & 63) < 32) atomicAdd(&sS[b], vp);
    __syncthreads();
    if (tid < 32) unsafeAtomicAdd(&S[tid], sS[tid]);
}

// ---------------------------------------------------------------------------
// outT: transpose E0 (NE,B) -> out0 (B,NE)
// ---------------------------------------------------------------------------
__global__ __launch_bounds__(256) void outT_kernel(
    const float* __restrict__ E0, float* __restrict__ out0)
{
    __shared__ float tile[32 * 33];
    int bid = blockIdx.x, tid = threadIdx.x;
    int base_e = bid * 32;
    #pragma unroll
    for (int l = 0; l < 4; ++l) {
        int idx = l * 256 + tid;
        int er = idx >> 5, br = idx & 31;                   // read coalesced
        tile[br * 33 + er] = E0[(size_t)(base_e + er) * 32 + br];
    }
    __syncthreads();
    #pragma unroll
    for (int l = 0; l < 4; ++l) {
        int idx = l * 256 + tid;
        int bw = idx >> 5, ew = idx & 31;                   // write coalesced
        out0[(size_t)bw * NE + base_e + ew] = tile[bw * 33 + ew];
    }
}

// ---------------------------------------------------------------------------
// gemm1: P[b,d] += sum_e E0[e,b] * emb[e,d]   (raw, scaled later)
// block handles 256 entities; thread owns d pair (2*tid, 2*tid+1) x 32 b
// ---------------------------------------------------------------------------
__global__ __launch_bounds__(256) void gemm1_kernel(
    const float* __restrict__ E0, const float* __restrict__ emb,
    float* __restrict__ P)
{
    __shared__ float evs[32 * 32];
    int tid = threadIdx.x;
    int base = blockIdx.x * 256;
    float acc0[32], acc1[32];
    #pragma unroll
    for (int b = 0; b < 32; ++b) { acc0[b] = 0.f; acc1[b] = 0.f; }
    const float2* emb2 = (const float2*)emb;

    for (int sg = 0; sg < 8; ++sg) {
        int ebase = base + sg * 32;
        __syncthreads();
        for (int k = tid; k < 1024; k += 256) {
            int ent = ebase + (k >> 5);
            evs[k] = (ent < NE) ? E0[(size_t)ent * 32 + (k & 31)] : 0.f;
        }
        __syncthreads();
        for (int i = 0; i < 32; ++i) {
            int ent = ebase + i; if (ent >= NE) ent = NE - 1;
            float2 w = emb2[(size_t)ent * 256 + tid];
            const float4* ev4 = (const float4*)(evs + i * 32);
            #pragma unroll
            for (int bg = 0; bg < 8; ++bg) {
                float4 e4 = ev4[bg];
                acc0[bg*4+0] += w.x * e4.x; acc1[bg*4+0] += w.y * e4.x;
                acc0[bg*4+1] += w.x * e4.y; acc1[bg*4+1] += w.y * e4.y;
                acc0[bg*4+2] += w.x * e4.z; acc1[bg*4+2] += w.y * e4.z;
                acc0[bg*4+3] += w.x * e4.w; acc1[bg*4+3] += w.y * e4.w;
            }
        }
    }
    int d0 = tid * 2;
    #pragma unroll
    for (int b = 0; b < 32; ++b) {
        unsafeAtomicAdd(&P[b * DH + d0],     acc0[b]);
        unsafeAtomicAdd(&P[b * DH + d0 + 1], acc1[b]);
    }
}

// ---------------------------------------------------------------------------
// gemm2: out1[b,e] = sum_d (P[b,d]/(S[b]+1e-6)) * emb[e,d] + bias[e]
// block: 512 entities (2 per thread); p staged+scaled in LDS (64 KB)
// ---------------------------------------------------------------------------
__global__ __launch_bounds__(256) void gemm2_kernel(
    const float* __restrict__ P, const float* __restrict__ S,
    const float* __restrict__ emb, const float* __restrict__ bias,
    float* __restrict__ out1)
{
    __shared__ float pl[B * DH];
    int tid = threadIdx.x;
    for (int k = tid; k < B * DH; k += 256) {
        int b = k >> 9;
        pl[k] = P[k] / (S[b] + 1e-6f);
    }
    __syncthreads();

    int base = blockIdx.x * 512;
    int e0 = base + tid, e1 = base + 256 + tid;
    int g0 = e0 < NE ? e0 : NE - 1;
    int g1 = e1 < NE ? e1 : NE - 1;
    const float4* emb4 = (const float4*)emb;
    const float4* pl4  = (const float4*)pl;

    float acc0[32], acc1[32];
    #pragma unroll
    for (int b = 0; b < 32; ++b) { acc0[b] = 0.f; acc1[b] = 0.f; }

    for (int dg = 0; dg < 128; ++dg) {
        float4 w0 = emb4[(size_t)g0 * 128 + dg];
        float4 w1 = emb4[(size_t)g1 * 128 + dg];
        #pragma unroll
        for (int b = 0; b < 32; ++b) {
            float4 pv = pl4[b * 128 + dg];      // broadcast
            acc0[b] += w0.x * pv.x + w0.y * pv.y + w0.z * pv.z + w0.w * pv.w;
            acc1[b] += w1.x * pv.x + w1.y * pv.y + w1.z * pv.z + w1.w * pv.w;
        }
    }
    float b0 = bias[g0], b1 = bias[g1];
    #pragma unroll
    for (int b = 0; b < 32; ++b) {
        if (e0 < NE) out1[(size_t)b * NE + e0] = acc0[b] + b0;
        if (e1 < NE) out1[(size_t)b * NE + e1] = acc1[b] + b1;
    }
}

// ---------------------------------------------------------------------------
extern "C" void kernel_launch(void* const* d_in, const int* in_sizes, int n_in,
                              void* d_out, int out_size, void* d_ws, size_t ws_size,
                              hipStream_t stream)
{
    const int*   questions = (const int*)d_in[0];
    const float* e_s       = (const float*)d_in[1];
    const float* answers   = (const float*)d_in[2];
    const int*   subj      = (const int*)d_in[3];
    const int*   rel       = (const int*)d_in[4];
    const int*   obj       = (const int*)d_in[5];
    const float* rel_emb   = (const float*)d_in[6];
    const float* step_W    = (const float*)d_in[7];
    const float* step_b    = (const float*)d_in[8];
    const float* ent_emb   = (const float*)d_in[9];
    const float* ent_bias  = (const float*)d_in[10];

    float* out0 = (float*)d_out;              // e_score (B,NE)
    float* out1 = out0 + (size_t)B * NE;      // pred_e  (B,NE)

    // workspace layout (needs ~38.5 MB)
    float* w  = (float*)d_ws;
    float* E0 = w;
    float* E1 = E0 + (size_t)NE * B;
    float* E2 = E1 + (size_t)NE * B;
    float* RD = E2 + (size_t)NE * B;          // rel_dist transposed (NR,B)
    float* P  = RD + NR * B;                  // (B,DH)
    float* S  = P + B * DH;                   // (B,)
    float* GT = S + B;                        // (B,)
    int* AM    = (int*)(GT + B);              // (3,B) argmaxes
    int* COND  = AM + 3 * B;                  // cond1 at COND, cond2 at COND+B
    int* FLAG3 = COND + 2 * B;                // (B,)
    int* SRC   = FLAG3 + B;                   // (B,)
    int* ANS   = SRC + B;                     // (B,)

    const int postGrid = NE * B / 256;        // 12500

    prep_kernel<<<NE / 32 + B, 256, 0, stream>>>(e_s, answers, E0, E1, SRC, ANS);

    // --- step 0 ---
    stepA_kernel<<<B, 256, 0, stream>>>(0, questions, rel_emb, step_W, step_b,
                                        RD, GT, AM, COND, FLAG3);
    follow_kernel<<<NT * 32 / 256, 256, 0, stream>>>(E0, E1, RD, subj, rel, obj);
    post0_kernel<<<postGrid, 256, 0, stream>>>(E1, E2, ANS, GT);

    // --- step 1 ---
    stepA_kernel<<<B, 256, 0, stream>>>(1, questions, rel_emb, step_W, step_b,
                                        RD, GT, AM, COND, FLAG3);
    follow_kernel<<<NT * 32 / 256, 256, 0, stream>>>(E1, E2, RD, subj, rel, obj);
    post1_kernel<<<postGrid, 256, 0, stream>>>(E2, E0, COND, SRC, P, S);

    // --- step 2 ---
    stepA_kernel<<<B, 256, 0, stream>>>(2, questions, rel_emb, step_W, step_b,
                                        RD, GT, AM, COND, FLAG3);
    follow_kernel<<<NT * 32 / 256, 256, 0, stream>>>(E2, E0, RD, subj, rel, obj);
    post2_kernel<<<postGrid, 256, 0, stream>>>(E0, E1, COND + B, SRC, FLAG3, S);

    // --- outputs ---
    outT_kernel<<<NE / 32, 256, 0, stream>>>(E0, out0);
    gemm1_kernel<<<(NE + 255) / 256, 256, 0, stream>>>(E0, ent_emb, P);
    gemm2_kernel<<<(NE + 511) / 512, 256, 0, stream>>>(P, S, ent_emb, ent_bias, out1);
}

// Round 2
// 1161.615 us; speedup vs baseline: 1.2715x; 1.2715x over previous
//
#include <hip/hip_runtime.h>
#include <math.h>

#define NE 100000
#define NR 400
#define NT 1000000
#define B  32
#define DH 512

// ---------------------------------------------------------------------------
// prep: transpose e_s (B,NE) -> E0 (NE,B); zero E1; extract src/ans one-hot
// idx inline during the transpose read (parallel across all 3125 blocks —
// the old dedicated 32-block scan was latency-serialized at ~335 us).
// ---------------------------------------------------------------------------
__global__ __launch_bounds__(256) void prep_kernel(
    const float* __restrict__ e_s, const float* __restrict__ answers,
    float* __restrict__ E0, float* __restrict__ E1,
    int* __restrict__ SRC, int* __restrict__ ANS)
{
    int bid = blockIdx.x, tid = threadIdx.x;
    __shared__ float tile[32 * 33];
    int base_e = bid * 32;
    #pragma unroll
    for (int l = 0; l < 4; ++l) {
        int idx = l * 256 + tid;
        int br = idx >> 5, ec = idx & 31;               // read coalesced over ec
        float v = e_s[(size_t)br * NE + base_e + ec];
        float a = answers[(size_t)br * NE + base_e + ec];
        tile[ec * 33 + br] = v;
        if (v > 0.5f) SRC[br] = base_e + ec;            // exactly one hit per b
        if (a > 0.5f) ANS[br] = base_e + ec;
    }
    __syncthreads();
    #pragma unroll
    for (int l = 0; l < 4; ++l) {
        int idx = l * 256 + tid;
        int ew = idx >> 5, bw = idx & 31;               // write coalesced over bw
        E0[(size_t)(base_e + ew) * 32 + bw] = tile[ew * 33 + bw];
        E1[(size_t)base_e * 32 + idx] = 0.f;
    }
}

// ---------------------------------------------------------------------------
// stepA: per-batch-row b: cq = tanh(q_emb @ W_t^T + b_t); logits = cq @ rel_emb^T;
// softmax -> RD (NR,B transposed); argmax; gt (t==0); cond flags (t>=1); flag3 (t==2)
// ---------------------------------------------------------------------------
__global__ __launch_bounds__(256) void stepA_kernel(
    int t,
    const int* __restrict__ questions,
    const float* __restrict__ rel_emb,
    const float* __restrict__ step_W,
    const float* __restrict__ step_b,
    float* __restrict__ RD, float* __restrict__ GT,
    int* __restrict__ AM, int* __restrict__ COND, int* __restrict__ FLAG3)
{
    __shared__ float qe[DH];
    __shared__ float cq[DH];
    __shared__ float lg[NR];
    __shared__ float rv[256];
    __shared__ int   ri[256];
    int b = blockIdx.x, tid = threadIdx.x;
    int q = questions[b];

    for (int i = tid; i < DH; i += 256) qe[i] = rel_emb[(size_t)q * DH + i];
    __syncthreads();

    for (int i = tid; i < DH; i += 256) {
        const float4* w4 = (const float4*)(step_W + ((size_t)t * DH + i) * DH);
        float acc = step_b[t * DH + i];
        for (int j = 0; j < DH / 4; ++j) {
            float4 wv = w4[j];
            acc += wv.x * qe[4*j] + wv.y * qe[4*j+1] + wv.z * qe[4*j+2] + wv.w * qe[4*j+3];
        }
        cq[i] = tanhf(acc);
    }
    __syncthreads();

    float lmax = -1e30f; int lidx = 0;
    for (int r = tid; r < NR; r += 256) {
        const float4* re4 = (const float4*)(rel_emb + (size_t)r * DH);
        float acc = 0.f;
        for (int j = 0; j < DH / 4; ++j) {
            float4 wv = re4[j];
            acc += wv.x * cq[4*j] + wv.y * cq[4*j+1] + wv.z * cq[4*j+2] + wv.w * cq[4*j+3];
        }
        lg[r] = acc;
        if (acc > lmax) { lmax = acc; lidx = r; }   // first-max kept (ascending r)
    }
    rv[tid] = lmax; ri[tid] = lidx;
    __syncthreads();
    for (int s = 128; s > 0; s >>= 1) {
        if (tid < s) {
            float ov = rv[tid + s]; int oi = ri[tid + s];
            if (ov > rv[tid] || (ov == rv[tid] && oi < ri[tid])) { rv[tid] = ov; ri[tid] = oi; }
        }
        __syncthreads();
    }
    float mx = rv[0]; int amax = ri[0];
    __syncthreads();

    float lsum = 0.f;
    for (int r = tid; r < NR; r += 256) {
        float ex = expf(lg[r] - mx);
        lg[r] = ex;
        lsum += ex;
    }
    rv[tid] = lsum;
    __syncthreads();
    for (int s = 128; s > 0; s >>= 1) {
        if (tid < s) rv[tid] += rv[tid + s];
        __syncthreads();
    }
    float Z = rv[0];

    for (int r = tid; r < NR; r += 256) RD[r * B + b] = lg[r] / Z;

    if (tid == 0) {
        AM[t * B + b] = amax;
        if (t == 0) GT[b] = lg[q] / Z;
        if (t >= 1) {
            int ap = AM[(t - 1) * B + b];
            int d = ap - amax; if (d < 0) d = -d;
            int mn = ap < amax ? ap : amax;
            COND[(t - 1) * B + b] = (d == 1 && (mn % 2 == 0)) ? 1 : 0;
        }
        if (t == 2) {
            int a0 = AM[0 * B + b], a1 = AM[1 * B + b];
            int c = (a0 == 0) + (a1 == 0) + (amax == 0);
            FLAG3[b] = (c == 1) ? 1 : 0;
        }
    }
}

// ---------------------------------------------------------------------------
// follow: Eout[obj,b] += Ein[subj,b] * RD[rel,b]  (skip zero contributions)
// ---------------------------------------------------------------------------
__global__ __launch_bounds__(256) void follow_kernel(
    const float* __restrict__ Ein, float* __restrict__ Eout,
    const float* __restrict__ RD,
    const int* __restrict__ subj, const int* __restrict__ rel,
    const int* __restrict__ obj)
{
    long long gid = (long long)blockIdx.x * 256 + threadIdx.x;
    int trip = (int)(gid >> 5);
    int b = threadIdx.x & 31;
    if (trip < NT) {
        int s = subj[trip];
        float ev = Ein[(size_t)s * 32 + b];
        if (ev != 0.f) {
            int r = rel[trip];
            int o = obj[trip];
            float x = ev * RD[r * B + b];
            if (x != 0.f) unsafeAtomicAdd(&Eout[(size_t)o * 32 + b], x);
        }
    }
}

// ---------------------------------------------------------------------------
// post0 (t=0): subtract answers*gt at ans position, clamp; zero E2
// ---------------------------------------------------------------------------
__global__ __launch_bounds__(256) void post0_kernel(
    float* __restrict__ E1, float* __restrict__ E2,
    const int* __restrict__ ANS, const float* __restrict__ GT)
{
    int idx = blockIdx.x * 256 + threadIdx.x;
    int b = idx & 31, e = idx >> 5;
    float v = E1[idx];
    if (e == ANS[b]) v -= GT[b];
    if (v > 1.f) v = 1.f;           // x/x == 1.0f exactly for x>1
    E1[idx] = v;
    E2[idx] = 0.f;
}

// ---------------------------------------------------------------------------
// post1 (t=1): clamp; targeted zero where cond1 && e==src (e_s>0.9 mask);
// zero E0, P, S for later stages
// ---------------------------------------------------------------------------
__global__ __launch_bounds__(256) void post1_kernel(
    float* __restrict__ E2, float* __restrict__ E0,
    const int* __restrict__ COND1, const int* __restrict__ SRC,
    float* __restrict__ P, float* __restrict__ S)
{
    int idx = blockIdx.x * 256 + threadIdx.x;
    int b = idx & 31, e = idx >> 5;
    float v = E2[idx];
    if (v > 1.f) v = 1.f;
    if (COND1[b] && e == SRC[b]) v = 0.f;
    E2[idx] = v;
    E0[idx] = 0.f;
    if (idx < B * DH) P[idx] = 0.f;
    if (idx < B)      S[idx] = 0.f;
}

// ---------------------------------------------------------------------------
// post2 (t=2): clamp; zero where cond2 && P0>0.9; zero where flag3 && e==src;
// accumulate per-b row sums S
// ---------------------------------------------------------------------------
__global__ __launch_bounds__(256) void post2_kernel(
    float* __restrict__ E0, const float* __restrict__ E1,
    const int* __restrict__ COND2, const int* __restrict__ SRC,
    const int* __restrict__ FLAG3, float* __restrict__ S)
{
    __shared__ float sS[32];
    int tid = threadIdx.x;
    int idx = blockIdx.x * 256 + tid;
    int b = idx & 31, e = idx >> 5;
    if (tid < 32) sS[tid] = 0.f;
    __syncthreads();
    float v = E0[idx];
    if (v > 1.f) v = 1.f;
    if (COND2[b] && E1[idx] > 0.9f) v = 0.f;
    if (FLAG3[b] && e == SRC[b]) v = 0.f;
    E0[idx] = v;
    float vp = v + __shfl_xor(v, 32, 64);   // lane and lane+32 share b
    if ((tid & 63) < 32) atomicAdd(&sS[b], vp);
    __syncthreads();
    if (tid < 32) unsafeAtomicAdd(&S[tid], sS[tid]);
}

// ---------------------------------------------------------------------------
// outT: transpose E0 (NE,B) -> out0 (B,NE)
// ---------------------------------------------------------------------------
__global__ __launch_bounds__(256) void outT_kernel(
    const float* __restrict__ E0, float* __restrict__ out0)
{
    __shared__ float tile[32 * 33];
    int bid = blockIdx.x, tid = threadIdx.x;
    int base_e = bid * 32;
    #pragma unroll
    for (int l = 0; l < 4; ++l) {
        int idx = l * 256 + tid;
        int er = idx >> 5, br = idx & 31;                   // read coalesced
        tile[br * 33 + er] = E0[(size_t)(base_e + er) * 32 + br];
    }
    __syncthreads();
    #pragma unroll
    for (int l = 0; l < 4; ++l) {
        int idx = l * 256 + tid;
        int bw = idx >> 5, ew = idx & 31;                   // write coalesced
        out0[(size_t)bw * NE + base_e + ew] = tile[bw * 33 + ew];
    }
}

// ---------------------------------------------------------------------------
// gemm1: P[b,d] += sum_e E0[e,b] * emb[e,d]   (raw, scaled later)
// block handles 256 entities; thread owns d pair (2*tid, 2*tid+1) x 32 b
// ---------------------------------------------------------------------------
__global__ __launch_bounds__(256) void gemm1_kernel(
    const float* __restrict__ E0, const float* __restrict__ emb,
    float* __restrict__ P)
{
    __shared__ float evs[32 * 32];
    int tid = threadIdx.x;
    int base = blockIdx.x * 256;
    float acc0[32], acc1[32];
    #pragma unroll
    for (int b = 0; b < 32; ++b) { acc0[b] = 0.f; acc1[b] = 0.f; }
    const float2* emb2 = (const float2*)emb;

    for (int sg = 0; sg < 8; ++sg) {
        int ebase = base + sg * 32;
        __syncthreads();
        for (int k = tid; k < 1024; k += 256) {
            int ent = ebase + (k >> 5);
            evs[k] = (ent < NE) ? E0[(size_t)ent * 32 + (k & 31)] : 0.f;
        }
        __syncthreads();
        for (int i = 0; i < 32; ++i) {
            int ent = ebase + i; if (ent >= NE) ent = NE - 1;
            float2 w = emb2[(size_t)ent * 256 + tid];
            const float4* ev4 = (const float4*)(evs + i * 32);
            #pragma unroll
            for (int bg = 0; bg < 8; ++bg) {
                float4 e4 = ev4[bg];
                acc0[bg*4+0] += w.x * e4.x; acc1[bg*4+0] += w.y * e4.x;
                acc0[bg*4+1] += w.x * e4.y; acc1[bg*4+1] += w.y * e4.y;
                acc0[bg*4+2] += w.x * e4.z; acc1[bg*4+2] += w.y * e4.z;
                acc0[bg*4+3] += w.x * e4.w; acc1[bg*4+3] += w.y * e4.w;
            }
        }
    }
    int d0 = tid * 2;
    #pragma unroll
    for (int b = 0; b < 32; ++b) {
        unsafeAtomicAdd(&P[b * DH + d0],     acc0[b]);
        unsafeAtomicAdd(&P[b * DH + d0 + 1], acc1[b]);
    }
}

// ---------------------------------------------------------------------------
// gemm2: out1[b,e] = sum_d (P[b,d]/(S[b]+1e-6)) * emb[e,d] + bias[e]
// block: 512 entities (2 per thread); p staged+scaled in LDS (64 KB)
// ---------------------------------------------------------------------------
__global__ __launch_bounds__(256) void gemm2_kernel(
    const float* __restrict__ P, const float* __restrict__ S,
    const float* __restrict__ emb, const float* __restrict__ bias,
    float* __restrict__ out1)
{
    __shared__ float pl[B * DH];
    int tid = threadIdx.x;
    for (int k = tid; k < B * DH; k += 256) {
        int b = k >> 9;
        pl[k] = P[k] / (S[b] + 1e-6f);
    }
    __syncthreads();

    int base = blockIdx.x * 512;
    int e0 = base + tid, e1 = base + 256 + tid;
    int g0 = e0 < NE ? e0 : NE - 1;
    int g1 = e1 < NE ? e1 : NE - 1;
    const float4* emb4 = (const float4*)emb;
    const float4* pl4  = (const float4*)pl;

    float acc0[32], acc1[32];
    #pragma unroll
    for (int b = 0; b < 32; ++b) { acc0[b] = 0.f; acc1[b] = 0.f; }

    for (int dg = 0; dg < 128; ++dg) {
        float4 w0 = emb4[(size_t)g0 * 128 + dg];
        float4 w1 = emb4[(size_t)g1 * 128 + dg];
        #pragma unroll
        for (int b = 0; b < 32; ++b) {
            float4 pv = pl4[b * 128 + dg];      // broadcast
            acc0[b] += w0.x * pv.x + w0.y * pv.y + w0.z * pv.z + w0.w * pv.w;
            acc1[b] += w1.x * pv.x + w1.y * pv.y + w1.z * pv.z + w1.w * pv.w;
        }
    }
    float b0 = bias[g0], b1 = bias[g1];
    #pragma unroll
    for (int b = 0; b < 32; ++b) {
        if (e0 < NE) out1[(size_t)b * NE + e0] = acc0[b] + b0;
        if (e1 < NE) out1[(size_t)b * NE + e1] = acc1[b] + b1;
    }
}

// ---------------------------------------------------------------------------
extern "C" void kernel_launch(void* const* d_in, const int* in_sizes, int n_in,
                              void* d_out, int out_size, void* d_ws, size_t ws_size,
                              hipStream_t stream)
{
    const int*   questions = (const int*)d_in[0];
    const float* e_s       = (const float*)d_in[1];
    const float* answers   = (const float*)d_in[2];
    const int*   subj      = (const int*)d_in[3];
    const int*   rel       = (const int*)d_in[4];
    const int*   obj       = (const int*)d_in[5];
    const float* rel_emb   = (const float*)d_in[6];
    const float* step_W    = (const float*)d_in[7];
    const float* step_b    = (const float*)d_in[8];
    const float* ent_emb   = (const float*)d_in[9];
    const float* ent_bias  = (const float*)d_in[10];

    float* out0 = (float*)d_out;              // e_score (B,NE)
    float* out1 = out0 + (size_t)B * NE;      // pred_e  (B,NE)

    // workspace layout (needs ~38.5 MB)
    float* w  = (float*)d_ws;
    float* E0 = w;
    float* E1 = E0 + (size_t)NE * B;
    float* E2 = E1 + (size_t)NE * B;
    float* RD = E2 + (size_t)NE * B;          // rel_dist transposed (NR,B)
    float* P  = RD + NR * B;                  // (B,DH)
    float* S  = P + B * DH;                   // (B,)
    float* GT = S + B;                        // (B,)
    int* AM    = (int*)(GT + B);              // (3,B) argmaxes
    int* COND  = AM + 3 * B;                  // cond1 at COND, cond2 at COND+B
    int* FLAG3 = COND + 2 * B;                // (B,)
    int* SRC   = FLAG3 + B;                   // (B,)
    int* ANS   = SRC + B;                     // (B,)

    const int postGrid = NE * B / 256;        // 12500

    prep_kernel<<<NE / 32, 256, 0, stream>>>(e_s, answers, E0, E1, SRC, ANS);

    // --- step 0 ---
    stepA_kernel<<<B, 256, 0, stream>>>(0, questions, rel_emb, step_W, step_b,
                                        RD, GT, AM, COND, FLAG3);
    follow_kernel<<<NT * 32 / 256, 256, 0, stream>>>(E0, E1, RD, subj, rel, obj);
    post0_kernel<<<postGrid, 256, 0, stream>>>(E1, E2, ANS, GT);

    // --- step 1 ---
    stepA_kernel<<<B, 256, 0, stream>>>(1, questions, rel_emb, step_W, step_b,
                                        RD, GT, AM, COND, FLAG3);
    follow_kernel<<<NT * 32 / 256, 256, 0, stream>>>(E1, E2, RD, subj, rel, obj);
    post1_kernel<<<postGrid, 256, 0, stream>>>(E2, E0, COND, SRC, P, S);

    // --- step 2 ---
    stepA_kernel<<<B, 256, 0, stream>>>(2, questions, rel_emb, step_W, step_b,
                                        RD, GT, AM, COND, FLAG3);
    follow_kernel<<<NT * 32 / 256, 256, 0, stream>>>(E2, E0, RD, subj, rel, obj);
    post2_kernel<<<postGrid, 256, 0, stream>>>(E0, E1, COND + B, SRC, FLAG3, S);

    // --- outputs ---
    outT_kernel<<<NE / 32, 256, 0, stream>>>(E0, out0);
    gemm1_kernel<<<(NE + 255) / 256, 256, 0, stream>>>(E0, ent_emb, P);
    gemm2_kernel<<<(NE + 511) / 512, 256, 0, stream>>>(P, S, ent_emb, ent_bias, out1);
}

// Round 3
// 937.929 us; speedup vs baseline: 1.5747x; 1.2385x over previous
//
#include <hip/hip_runtime.h>
#include <math.h>

#define NE 100000
#define NR 400
#define NT 1000000
#define B  32
#define DH 512

// ---------------------------------------------------------------------------
// prep: transpose e_s (B,NE) -> E0 (NE,B); zero E1; extract src/ans one-hot
// idx inline during the transpose read (parallel across all 3125 blocks —
// the old dedicated 32-block scan was latency-serialized at ~335 us).
// ---------------------------------------------------------------------------
__global__ __launch_bounds__(256) void prep_kernel(
    const float* __restrict__ e_s, const float* __restrict__ answers,
    float* __restrict__ E0, float* __restrict__ E1,
    int* __restrict__ SRC, int* __restrict__ ANS)
{
    int bid = blockIdx.x, tid = threadIdx.x;
    __shared__ float tile[32 * 33];
    int base_e = bid * 32;
    #pragma unroll
    for (int l = 0; l < 4; ++l) {
        int idx = l * 256 + tid;
        int br = idx >> 5, ec = idx & 31;               // read coalesced over ec
        float v = e_s[(size_t)br * NE + base_e + ec];
        float a = answers[(size_t)br * NE + base_e + ec];
        tile[ec * 33 + br] = v;
        if (v > 0.5f) SRC[br] = base_e + ec;            // exactly one hit per b
        if (a > 0.5f) ANS[br] = base_e + ec;
    }
    __syncthreads();
    #pragma unroll
    for (int l = 0; l < 4; ++l) {
        int idx = l * 256 + tid;
        int ew = idx >> 5, bw = idx & 31;               // write coalesced over bw
        E0[(size_t)(base_e + ew) * 32 + bw] = tile[ew * 33 + bw];
        E1[(size_t)base_e * 32 + idx] = 0.f;
    }
}

// ---------------------------------------------------------------------------
// stepA: per-batch-row b: cq = tanh(q_emb @ W_t^T + b_t); logits = cq @ rel_emb^T;
// softmax -> RD (NR,B transposed); argmax; gt (t==0); cond flags (t>=1); flag3 (t==2)
// ---------------------------------------------------------------------------
__global__ __launch_bounds__(256) void stepA_kernel(
    int t,
    const int* __restrict__ questions,
    const float* __restrict__ rel_emb,
    const float* __restrict__ step_W,
    const float* __restrict__ step_b,
    float* __restrict__ RD, float* __restrict__ GT,
    int* __restrict__ AM, int* __restrict__ COND, int* __restrict__ FLAG3)
{
    __shared__ float qe[DH];
    __shared__ float cq[DH];
    __shared__ float lg[NR];
    __shared__ float rv[256];
    __shared__ int   ri[256];
    int b = blockIdx.x, tid = threadIdx.x;
    int q = questions[b];

    for (int i = tid; i < DH; i += 256) qe[i] = rel_emb[(size_t)q * DH + i];
    __syncthreads();

    for (int i = tid; i < DH; i += 256) {
        const float4* w4 = (const float4*)(step_W + ((size_t)t * DH + i) * DH);
        float acc = step_b[t * DH + i];
        for (int j = 0; j < DH / 4; ++j) {
            float4 wv = w4[j];
            acc += wv.x * qe[4*j] + wv.y * qe[4*j+1] + wv.z * qe[4*j+2] + wv.w * qe[4*j+3];
        }
        cq[i] = tanhf(acc);
    }
    __syncthreads();

    float lmax = -1e30f; int lidx = 0;
    for (int r = tid; r < NR; r += 256) {
        const float4* re4 = (const float4*)(rel_emb + (size_t)r * DH);
        float acc = 0.f;
        for (int j = 0; j < DH / 4; ++j) {
            float4 wv = re4[j];
            acc += wv.x * cq[4*j] + wv.y * cq[4*j+1] + wv.z * cq[4*j+2] + wv.w * cq[4*j+3];
        }
        lg[r] = acc;
        if (acc > lmax) { lmax = acc; lidx = r; }   // first-max kept (ascending r)
    }
    rv[tid] = lmax; ri[tid] = lidx;
    __syncthreads();
    for (int s = 128; s > 0; s >>= 1) {
        if (tid < s) {
            float ov = rv[tid + s]; int oi = ri[tid + s];
            if (ov > rv[tid] || (ov == rv[tid] && oi < ri[tid])) { rv[tid] = ov; ri[tid] = oi; }
        }
        __syncthreads();
    }
    float mx = rv[0]; int amax = ri[0];
    __syncthreads();

    float lsum = 0.f;
    for (int r = tid; r < NR; r += 256) {
        float ex = expf(lg[r] - mx);
        lg[r] = ex;
        lsum += ex;
    }
    rv[tid] = lsum;
    __syncthreads();
    for (int s = 128; s > 0; s >>= 1) {
        if (tid < s) rv[tid] += rv[tid + s];
        __syncthreads();
    }
    float Z = rv[0];

    for (int r = tid; r < NR; r += 256) RD[r * B + b] = lg[r] / Z;

    if (tid == 0) {
        AM[t * B + b] = amax;
        if (t == 0) GT[b] = lg[q] / Z;
        if (t >= 1) {
            int ap = AM[(t - 1) * B + b];
            int d = ap - amax; if (d < 0) d = -d;
            int mn = ap < amax ? ap : amax;
            COND[(t - 1) * B + b] = (d == 1 && (mn % 2 == 0)) ? 1 : 0;
        }
        if (t == 2) {
            int a0 = AM[0 * B + b], a1 = AM[1 * B + b];
            int c = (a0 == 0) + (a1 == 0) + (amax == 0);
            FLAG3[b] = (c == 1) ? 1 : 0;
        }
    }
}

// ---------------------------------------------------------------------------
// follow: Eout[obj,b] += Ein[subj,b] * RD[rel,b]  (skip zero contributions)
// ---------------------------------------------------------------------------
__global__ __launch_bounds__(256) void follow_kernel(
    const float* __restrict__ Ein, float* __restrict__ Eout,
    const float* __restrict__ RD,
    const int* __restrict__ subj, const int* __restrict__ rel,
    const int* __restrict__ obj)
{
    long long gid = (long long)blockIdx.x * 256 + threadIdx.x;
    int trip = (int)(gid >> 5);
    int b = threadIdx.x & 31;
    if (trip < NT) {
        int s = subj[trip];
        float ev = Ein[(size_t)s * 32 + b];
        if (ev != 0.f) {
            int r = rel[trip];
            int o = obj[trip];
            float x = ev * RD[r * B + b];
            if (x != 0.f) unsafeAtomicAdd(&Eout[(size_t)o * 32 + b], x);
        }
    }
}

// ---------------------------------------------------------------------------
// post0 (t=0): subtract answers*gt at ans position, clamp; zero E2
// ---------------------------------------------------------------------------
__global__ __launch_bounds__(256) void post0_kernel(
    float* __restrict__ E1, float* __restrict__ E2,
    const int* __restrict__ ANS, const float* __restrict__ GT)
{
    int idx = blockIdx.x * 256 + threadIdx.x;
    int b = idx & 31, e = idx >> 5;
    float v = E1[idx];
    if (e == ANS[b]) v -= GT[b];
    if (v > 1.f) v = 1.f;           // x/x == 1.0f exactly for x>1
    E1[idx] = v;
    E2[idx] = 0.f;
}

// ---------------------------------------------------------------------------
// post1 (t=1): clamp; targeted zero where cond1 && e==src (e_s>0.9 mask);
// zero E0, P, S for later stages
// ---------------------------------------------------------------------------
__global__ __launch_bounds__(256) void post1_kernel(
    float* __restrict__ E2, float* __restrict__ E0,
    const int* __restrict__ COND1, const int* __restrict__ SRC,
    float* __restrict__ P, float* __restrict__ S)
{
    int idx = blockIdx.x * 256 + threadIdx.x;
    int b = idx & 31, e = idx >> 5;
    float v = E2[idx];
    if (v > 1.f) v = 1.f;
    if (COND1[b] && e == SRC[b]) v = 0.f;
    E2[idx] = v;
    E0[idx] = 0.f;
    if (idx < B * DH) P[idx] = 0.f;
    if (idx < B)      S[idx] = 0.f;
}

// ---------------------------------------------------------------------------
// post2 (t=2): clamp; zero where cond2 && P0>0.9; zero where flag3 && e==src;
// accumulate per-b row sums S.
// Grid-stride with 512 blocks: the old 12500-block version issued 12500
// same-line atomics to S (13 ns each, serialized = 163 us). 512 blocks
// keep full BW for the elementwise part and cut atomic serialization 24x.
// Stride 512*256 is a multiple of 32, so b = tid&31 is loop-invariant.
// ---------------------------------------------------------------------------
#define POST2_BLOCKS 512
__global__ __launch_bounds__(256) void post2_kernel(
    float* __restrict__ E0, const float* __restrict__ E1,
    const int* __restrict__ COND2, const int* __restrict__ SRC,
    const int* __restrict__ FLAG3, float* __restrict__ S)
{
    __shared__ float sS[32];
    int tid = threadIdx.x;
    int b = tid & 31;
    if (tid < 32) sS[tid] = 0.f;
    __syncthreads();

    int c2 = COND2[b];
    int f3 = FLAG3[b];
    int sr = SRC[b];

    float local = 0.f;
    for (int idx = blockIdx.x * 256 + tid; idx < NE * B; idx += POST2_BLOCKS * 256) {
        int e = idx >> 5;
        float v = E0[idx];
        if (v > 1.f) v = 1.f;
        if (c2 && E1[idx] > 0.9f) v = 0.f;
        if (f3 && e == sr) v = 0.f;
        E0[idx] = v;
        local += v;
    }
    local += __shfl_xor(local, 32, 64);     // lane and lane+32 share b
    if ((tid & 63) < 32) atomicAdd(&sS[b], local);
    __syncthreads();
    if (tid < 32) unsafeAtomicAdd(&S[tid], sS[tid]);
}

// ---------------------------------------------------------------------------
// outT: transpose E0 (NE,B) -> out0 (B,NE)
// ---------------------------------------------------------------------------
__global__ __launch_bounds__(256) void outT_kernel(
    const float* __restrict__ E0, float* __restrict__ out0)
{
    __shared__ float tile[32 * 33];
    int bid = blockIdx.x, tid = threadIdx.x;
    int base_e = bid * 32;
    #pragma unroll
    for (int l = 0; l < 4; ++l) {
        int idx = l * 256 + tid;
        int er = idx >> 5, br = idx & 31;                   // read coalesced
        tile[br * 33 + er] = E0[(size_t)(base_e + er) * 32 + br];
    }
    __syncthreads();
    #pragma unroll
    for (int l = 0; l < 4; ++l) {
        int idx = l * 256 + tid;
        int bw = idx >> 5, ew = idx & 31;                   // write coalesced
        out0[(size_t)bw * NE + base_e + ew] = tile[bw * 33 + ew];
    }
}

// ---------------------------------------------------------------------------
// gemm1: P[b,d] += sum_e E0[e,b] * emb[e,d]   (raw, scaled later)
// block handles 256 entities; thread owns d pair (2*tid, 2*tid+1) x 32 b
// ---------------------------------------------------------------------------
__global__ __launch_bounds__(256) void gemm1_kernel(
    const float* __restrict__ E0, const float* __restrict__ emb,
    float* __restrict__ P)
{
    __shared__ float evs[32 * 32];
    int tid = threadIdx.x;
    int base = blockIdx.x * 256;
    float acc0[32], acc1[32];
    #pragma unroll
    for (int b = 0; b < 32; ++b) { acc0[b] = 0.f; acc1[b] = 0.f; }
    const float2* emb2 = (const float2*)emb;

    for (int sg = 0; sg < 8; ++sg) {
        int ebase = base + sg * 32;
        __syncthreads();
        for (int k = tid; k < 1024; k += 256) {
            int ent = ebase + (k >> 5);
            evs[k] = (ent < NE) ? E0[(size_t)ent * 32 + (k & 31)] : 0.f;
        }
        __syncthreads();
        for (int i = 0; i < 32; ++i) {
            int ent = ebase + i; if (ent >= NE) ent = NE - 1;
            float2 w = emb2[(size_t)ent * 256 + tid];
            const float4* ev4 = (const float4*)(evs + i * 32);
            #pragma unroll
            for (int bg = 0; bg < 8; ++bg) {
                float4 e4 = ev4[bg];
                acc0[bg*4+0] += w.x * e4.x; acc1[bg*4+0] += w.y * e4.x;
                acc0[bg*4+1] += w.x * e4.y; acc1[bg*4+1] += w.y * e4.y;
                acc0[bg*4+2] += w.x * e4.z; acc1[bg*4+2] += w.y * e4.z;
                acc0[bg*4+3] += w.x * e4.w; acc1[bg*4+3] += w.y * e4.w;
            }
        }
    }
    int d0 = tid * 2;
    #pragma unroll
    for (int b = 0; b < 32; ++b) {
        unsafeAtomicAdd(&P[b * DH + d0],     acc0[b]);
        unsafeAtomicAdd(&P[b * DH + d0 + 1], acc1[b]);
    }
}

// ---------------------------------------------------------------------------
// gemm2: out1[b,e] = sum_d (P[b,d]/(S[b]+1e-6)) * emb[e,d] + bias[e]
// block: 512 entities (2 per thread); p staged+scaled in LDS (64 KB)
// ---------------------------------------------------------------------------
__global__ __launch_bounds__(256) void gemm2_kernel(
    const float* __restrict__ P, const float* __restrict__ S,
    const float* __restrict__ emb, const float* __restrict__ bias,
    float* __restrict__ out1)
{
    __shared__ float pl[B * DH];
    int tid = threadIdx.x;
    for (int k = tid; k < B * DH; k += 256) {
        int b = k >> 9;
        pl[k] = P[k] / (S[b] + 1e-6f);
    }
    __syncthreads();

    int base = blockIdx.x * 512;
    int e0 = base + tid, e1 = base + 256 + tid;
    int g0 = e0 < NE ? e0 : NE - 1;
    int g1 = e1 < NE ? e1 : NE - 1;
    const float4* emb4 = (const float4*)emb;
    const float4* pl4  = (const float4*)pl;

    float acc0[32], acc1[32];
    #pragma unroll
    for (int b = 0; b < 32; ++b) { acc0[b] = 0.f; acc1[b] = 0.f; }

    for (int dg = 0; dg < 128; ++dg) {
        float4 w0 = emb4[(size_t)g0 * 128 + dg];
        float4 w1 = emb4[(size_t)g1 * 128 + dg];
        #pragma unroll
        for (int b = 0; b < 32; ++b) {
            float4 pv = pl4[b * 128 + dg];      // broadcast
            acc0[b] += w0.x * pv.x + w0.y * pv.y + w0.z * pv.z + w0.w * pv.w;
            acc1[b] += w1.x * pv.x + w1.y * pv.y + w1.z * pv.z + w1.w * pv.w;
        }
    }
    float b0 = bias[g0], b1 = bias[g1];
    #pragma unroll
    for (int b = 0; b < 32; ++b) {
        if (e0 < NE) out1[(size_t)b * NE + e0] = acc0[b] + b0;
        if (e1 < NE) out1[(size_t)b * NE + e1] = acc1[b] + b1;
    }
}

// ---------------------------------------------------------------------------
extern "C" void kernel_launch(void* const* d_in, const int* in_sizes, int n_in,
                              void* d_out, int out_size, void* d_ws, size_t ws_size,
                              hipStream_t stream)
{
    const int*   questions = (const int*)d_in[0];
    const float* e_s       = (const float*)d_in[1];
    const float* answers   = (const float*)d_in[2];
    const int*   subj      = (const int*)d_in[3];
    const int*   rel       = (const int*)d_in[4];
    const int*   obj       = (const int*)d_in[5];
    const float* rel_emb   = (const float*)d_in[6];
    const float* step_W    = (const float*)d_in[7];
    const float* step_b    = (const float*)d_in[8];
    const float* ent_emb   = (const float*)d_in[9];
    const float* ent_bias  = (const float*)d_in[10];

    float* out0 = (float*)d_out;              // e_score (B,NE)
    float* out1 = out0 + (size_t)B * NE;      // pred_e  (B,NE)

    // workspace layout (needs ~38.5 MB)
    float* w  = (float*)d_ws;
    float* E0 = w;
    float* E1 = E0 + (size_t)NE * B;
    float* E2 = E1 + (size_t)NE * B;
    float* RD = E2 + (size_t)NE * B;          // rel_dist transposed (NR,B)
    float* P  = RD + NR * B;                  // (B,DH)
    float* S  = P + B * DH;                   // (B,)
    float* GT = S + B;                        // (B,)
    int* AM    = (int*)(GT + B);              // (3,B) argmaxes
    int* COND  = AM + 3 * B;                  // cond1 at COND, cond2 at COND+B
    int* FLAG3 = COND + 2 * B;                // (B,)
    int* SRC   = FLAG3 + B;                   // (B,)
    int* ANS   = SRC + B;                     // (B,)

    const int postGrid = NE * B / 256;        // 12500

    prep_kernel<<<NE / 32, 256, 0, stream>>>(e_s, answers, E0, E1, SRC, ANS);

    // --- step 0 ---
    stepA_kernel<<<B, 256, 0, stream>>>(0, questions, rel_emb, step_W, step_b,
                                        RD, GT, AM, COND, FLAG3);
    follow_kernel<<<NT * 32 / 256, 256, 0, stream>>>(E0, E1, RD, subj, rel, obj);
    post0_kernel<<<postGrid, 256, 0, stream>>>(E1, E2, ANS, GT);

    // --- step 1 ---
    stepA_kernel<<<B, 256, 0, stream>>>(1, questions, rel_emb, step_W, step_b,
                                        RD, GT, AM, COND, FLAG3);
    follow_kernel<<<NT * 32 / 256, 256, 0, stream>>>(E1, E2, RD, subj, rel, obj);
    post1_kernel<<<postGrid, 256, 0, stream>>>(E2, E0, COND, SRC, P, S);

    // --- step 2 ---
    stepA_kernel<<<B, 256, 0, stream>>>(2, questions, rel_emb, step_W, step_b,
                                        RD, GT, AM, COND, FLAG3);
    follow_kernel<<<NT * 32 / 256, 256, 0, stream>>>(E2, E0, RD, subj, rel, obj);
    post2_kernel<<<POST2_BLOCKS, 256, 0, stream>>>(E0, E1, COND + B, SRC, FLAG3, S);

    // --- outputs ---
    outT_kernel<<<NE / 32, 256, 0, stream>>>(E0, out0);
    gemm1_kernel<<<(NE + 255) / 256, 256, 0, stream>>>(E0, ent_emb, P);
    gemm2_kernel<<<(NE + 511) / 512, 256, 0, stream>>>(P, S, ent_emb, ent_bias, out1);
}

// Round 5
// 863.760 us; speedup vs baseline: 1.7099x; 1.0859x over previous
//
#include <hip/hip_runtime.h>
#include <math.h>

#define NE 100000
#define NR 400
#define NT 1000000
#define B  32
#define DH 512

// ---------------------------------------------------------------------------
// prep: transpose e_s (B,NE) -> E0 (NE,B); zero E1; extract src/ans one-hot
// idx inline during the transpose read.
// ---------------------------------------------------------------------------
__global__ __launch_bounds__(256) void prep_kernel(
    const float* __restrict__ e_s, const float* __restrict__ answers,
    float* __restrict__ E0, float* __restrict__ E1,
    int* __restrict__ SRC, int* __restrict__ ANS)
{
    int bid = blockIdx.x, tid = threadIdx.x;
    __shared__ float tile[32 * 33];
    int base_e = bid * 32;
    #pragma unroll
    for (int l = 0; l < 4; ++l) {
        int idx = l * 256 + tid;
        int br = idx >> 5, ec = idx & 31;               // read coalesced over ec
        float v = e_s[(size_t)br * NE + base_e + ec];
        float a = answers[(size_t)br * NE + base_e + ec];
        tile[ec * 33 + br] = v;
        if (v > 0.5f) SRC[br] = base_e + ec;            // exactly one hit per b
        if (a > 0.5f) ANS[br] = base_e + ec;
    }
    __syncthreads();
    #pragma unroll
    for (int l = 0; l < 4; ++l) {
        int idx = l * 256 + tid;
        int ew = idx >> 5, bw = idx & 31;               // write coalesced over bw
        E0[(size_t)(base_e + ew) * 32 + bw] = tile[ew * 33 + bw];
        E1[(size_t)base_e * 32 + idx] = 0.f;
    }
}

// ---------------------------------------------------------------------------
// stepA: per-batch-row b: cq = tanh(q_emb @ W_t^T + b_t); logits = cq @ rel_emb^T;
// softmax -> RD (NR,B transposed); argmax; gt (t==0); cond flags (t>=1); flag3 (t==2)
// ---------------------------------------------------------------------------
__global__ __launch_bounds__(256) void stepA_kernel(
    int t,
    const int* __restrict__ questions,
    const float* __restrict__ rel_emb,
    const float* __restrict__ step_W,
    const float* __restrict__ step_b,
    float* __restrict__ RD, float* __restrict__ GT,
    int* __restrict__ AM, int* __restrict__ COND, int* __restrict__ FLAG3)
{
    __shared__ float qe[DH];
    __shared__ float cq[DH];
    __shared__ float lg[NR];
    __shared__ float rv[256];
    __shared__ int   ri[256];
    int b = blockIdx.x, tid = threadIdx.x;
    int q = questions[b];

    for (int i = tid; i < DH; i += 256) qe[i] = rel_emb[(size_t)q * DH + i];
    __syncthreads();

    for (int i = tid; i < DH; i += 256) {
        const float4* w4 = (const float4*)(step_W + ((size_t)t * DH + i) * DH);
        float acc = step_b[t * DH + i];
        for (int j = 0; j < DH / 4; ++j) {
            float4 wv = w4[j];
            acc += wv.x * qe[4*j] + wv.y * qe[4*j+1] + wv.z * qe[4*j+2] + wv.w * qe[4*j+3];
        }
        cq[i] = tanhf(acc);
    }
    __syncthreads();

    float lmax = -1e30f; int lidx = 0;
    for (int r = tid; r < NR; r += 256) {
        const float4* re4 = (const float4*)(rel_emb + (size_t)r * DH);
        float acc = 0.f;
        for (int j = 0; j < DH / 4; ++j) {
            float4 wv = re4[j];
            acc += wv.x * cq[4*j] + wv.y * cq[4*j+1] + wv.z * cq[4*j+2] + wv.w * cq[4*j+3];
        }
        lg[r] = acc;
        if (acc > lmax) { lmax = acc; lidx = r; }   // first-max kept (ascending r)
    }
    rv[tid] = lmax; ri[tid] = lidx;
    __syncthreads();
    for (int s = 128; s > 0; s >>= 1) {
        if (tid < s) {
            float ov = rv[tid + s]; int oi = ri[tid + s];
            if (ov > rv[tid] || (ov == rv[tid] && oi < ri[tid])) { rv[tid] = ov; ri[tid] = oi; }
        }
        __syncthreads();
    }
    float mx = rv[0]; int amax = ri[0];
    __syncthreads();

    float lsum = 0.f;
    for (int r = tid; r < NR; r += 256) {
        float ex = expf(lg[r] - mx);
        lg[r] = ex;
        lsum += ex;
    }
    rv[tid] = lsum;
    __syncthreads();
    for (int s = 128; s > 0; s >>= 1) {
        if (tid < s) rv[tid] += rv[tid + s];
        __syncthreads();
    }
    float Z = rv[0];

    for (int r = tid; r < NR; r += 256) RD[r * B + b] = lg[r] / Z;

    if (tid == 0) {
        AM[t * B + b] = amax;
        if (t == 0) GT[b] = lg[q] / Z;
        if (t >= 1) {
            int ap = AM[(t - 1) * B + b];
            int d = ap - amax; if (d < 0) d = -d;
            int mn = ap < amax ? ap : amax;
            COND[(t - 1) * B + b] = (d == 1 && (mn % 2 == 0)) ? 1 : 0;
        }
        if (t == 2) {
            int a0 = AM[0 * B + b], a1 = AM[1 * B + b];
            int c = (a0 == 0) + (a1 == 0) + (amax == 0);
            FLAG3[b] = (c == 1) ? 1 : 0;
        }
    }
}

// ---------------------------------------------------------------------------
// follow: Eout[obj,b] += Ein[subj,b] * RD[rel,b]  (skip zero contributions)
// ---------------------------------------------------------------------------
__global__ __launch_bounds__(256) void follow_kernel(
    const float* __restrict__ Ein, float* __restrict__ Eout,
    const float* __restrict__ RD,
    const int* __restrict__ subj, const int* __restrict__ rel,
    const int* __restrict__ obj)
{
    long long gid = (long long)blockIdx.x * 256 + threadIdx.x;
    int trip = (int)(gid >> 5);
    int b = threadIdx.x & 31;
    if (trip < NT) {
        int s = subj[trip];
        float ev = Ein[(size_t)s * 32 + b];
        if (ev != 0.f) {
            int r = rel[trip];
            int o = obj[trip];
            float x = ev * RD[r * B + b];
            if (x != 0.f) unsafeAtomicAdd(&Eout[(size_t)o * 32 + b], x);
        }
    }
}

// ---------------------------------------------------------------------------
// post0 (t=0): subtract answers*gt at ans position, clamp; zero E2
// ---------------------------------------------------------------------------
__global__ __launch_bounds__(256) void post0_kernel(
    float* __restrict__ E1, float* __restrict__ E2,
    const int* __restrict__ ANS, const float* __restrict__ GT)
{
    int idx = blockIdx.x * 256 + threadIdx.x;
    int b = idx & 31, e = idx >> 5;
    float v = E1[idx];
    if (e == ANS[b]) v -= GT[b];
    if (v > 1.f) v = 1.f;           // x/x == 1.0f exactly for x>1
    E1[idx] = v;
    E2[idx] = 0.f;
}

// ---------------------------------------------------------------------------
// post1 (t=1): clamp; targeted zero where cond1 && e==src (e_s>0.9 mask);
// zero E0, P, S, COUNT for later stages
// ---------------------------------------------------------------------------
__global__ __launch_bounds__(256) void post1_kernel(
    float* __restrict__ E2, float* __restrict__ E0,
    const int* __restrict__ COND1, const int* __restrict__ SRC,
    float* __restrict__ P, float* __restrict__ S, int* __restrict__ CNT)
{
    int idx = blockIdx.x * 256 + threadIdx.x;
    int b = idx & 31, e = idx >> 5;
    float v = E2[idx];
    if (v > 1.f) v = 1.f;
    if (COND1[b] && e == SRC[b]) v = 0.f;
    E2[idx] = v;
    E0[idx] = 0.f;
    if (idx < B * DH) P[idx] = 0.f;
    if (idx < B)      S[idx] = 0.f;
    if (idx == 0)     CNT[0] = 0;
}

// ---------------------------------------------------------------------------
// post2 (t=2): clamp; zero where cond2 && P0>0.9; zero where flag3 && e==src;
// accumulate per-b row sums S; build compacted list of entities whose final
// E0 row has any nonzero (support of e_score — used by sparse gemm1).
// Grid-stride 512 blocks; per block <= 200 entities, so lbuf[200] suffices.
// ---------------------------------------------------------------------------
#define POST2_BLOCKS 512
__global__ __launch_bounds__(256) void post2_kernel(
    float* __restrict__ E0, const float* __restrict__ E1,
    const int* __restrict__ COND2, const int* __restrict__ SRC,
    const int* __restrict__ FLAG3, float* __restrict__ S,
    int* __restrict__ LIST, int* __restrict__ CNT)
{
    __shared__ float sS[32];
    __shared__ int   lbuf[200];
    __shared__ int   lcnt;
    __shared__ int   lbase;
    int tid = threadIdx.x;
    int b = tid & 31;
    if (tid < 32) sS[tid] = 0.f;
    if (tid == 0) lcnt = 0;
    __syncthreads();

    int c2 = COND2[b];
    int f3 = FLAG3[b];
    int sr = SRC[b];

    float local = 0.f;
    // NE*B = 3.2e6 is a multiple of 256, so every active block iteration has
    // all 256 threads active (ballot sees full waves).
    for (int idx = blockIdx.x * 256 + tid; idx < NE * B; idx += POST2_BLOCKS * 256) {
        int e = idx >> 5;
        float v = E0[idx];
        if (v > 1.f) v = 1.f;
        if (c2 && E1[idx] > 0.9f) v = 0.f;
        if (f3 && e == sr) v = 0.f;
        E0[idx] = v;
        local += v;
        unsigned long long m = __ballot(v != 0.f);
        int lane = tid & 63;
        if (lane == 0 && (unsigned)(m & 0xffffffffULL)) {
            int p = atomicAdd(&lcnt, 1); lbuf[p] = e;
        }
        if (lane == 32 && (unsigned)(m >> 32)) {
            int p = atomicAdd(&lcnt, 1); lbuf[p] = e;
        }
    }
    local += __shfl_xor(local, 32, 64);     // lane and lane+32 share b
    if ((tid & 63) < 32) atomicAdd(&sS[b], local);
    __syncthreads();
    if (tid < 32) unsafeAtomicAdd(&S[tid], sS[tid]);
    if (tid == 0) lbase = atomicAdd(CNT, lcnt);
    __syncthreads();
    for (int i = tid; i < lcnt; i += 256) LIST[lbase + i] = lbuf[i];
}

// ---------------------------------------------------------------------------
// outT: transpose E0 (NE,B) -> out0 (B,NE)
// ---------------------------------------------------------------------------
__global__ __launch_bounds__(256) void outT_kernel(
    const float* __restrict__ E0, float* __restrict__ out0)
{
    __shared__ float tile[32 * 33];
    int bid = blockIdx.x, tid = threadIdx.x;
    int base_e = bid * 32;
    #pragma unroll
    for (int l = 0; l < 4; ++l) {
        int idx = l * 256 + tid;
        int er = idx >> 5, br = idx & 31;                   // read coalesced
        tile[br * 33 + er] = E0[(size_t)(base_e + er) * 32 + br];
    }
    __syncthreads();
    #pragma unroll
    for (int l = 0; l < 4; ++l) {
        int idx = l * 256 + tid;
        int bw = idx >> 5, ew = idx & 31;                   // write coalesced
        out0[(size_t)bw * NE + base_e + ew] = tile[bw * 33 + ew];
    }
}

// ---------------------------------------------------------------------------
// gemm1 (sparse): P_part[lc][b][d] = sum_{e in LIST chunk lc} E0[e,b]*emb[e,d]
// Support of E0 is ~1k entities/row -> union ~25-30k of 100k; the old dense
// version streamed all 205 MB of emb (158 us, latency-bound) and finished
// with 6.4M same-line atomics. Here: 512 blocks = 128 list-chunks x 4
// d-chunks(128); per entity a wave does 1 coalesced float2 emb load + 2
// broadcast float4 E0 loads + 16 FMA; plain-store partials, no atomics.
// NOTE: macro params must not be named x/y/z/w — `.w` member tokens inside
// the body would get substituted (R3 compile failure).
// ---------------------------------------------------------------------------
#define G1_LC 128
#define G1_BLOCKS (G1_LC * 4)

__global__ __launch_bounds__(256) void gemm1_kernel(
    const float* __restrict__ E0, const float* __restrict__ emb,
    const int* __restrict__ LIST, const int* __restrict__ CNT,
    float* __restrict__ PPART)
{
    int tid = threadIdx.x;
    int dc  = blockIdx.x & 3;          // which 128-d chunk
    int lc  = blockIdx.x >> 2;         // list chunk 0..G1_LC-1
    int bg  = tid >> 6;                // wave -> 8-b group
    int dl  = tid & 63;                // float2 lane within d chunk
    int cnt = CNT[0];
    const float2* emb2 = (const float2*)emb;
    int off2 = dc * 64 + dl;

    float2 acc[8];
    #pragma unroll
    for (int k = 0; k < 8; ++k) { acc[k].x = 0.f; acc[k].y = 0.f; }

#define G1_FMA(Wv, Ev, kk) \
    acc[kk+0].x += Ev.x * Wv.x; acc[kk+0].y += Ev.x * Wv.y; \
    acc[kk+1].x += Ev.y * Wv.x; acc[kk+1].y += Ev.y * Wv.y; \
    acc[kk+2].x += Ev.z * Wv.x; acc[kk+2].y += Ev.z * Wv.y; \
    acc[kk+3].x += Ev.w * Wv.x; acc[kk+3].y += Ev.w * Wv.y;

    int i = lc;
    for (; i + G1_LC < cnt; i += 2 * G1_LC) {           // unroll-2 for MLP
        int ei0 = LIST[i];
        int ei1 = LIST[i + G1_LC];
        float2 w0 = emb2[(size_t)ei0 * 256 + off2];
        float4 a0 = *(const float4*)(E0 + (size_t)ei0 * 32 + bg * 8);
        float4 b0 = *(const float4*)(E0 + (size_t)ei0 * 32 + bg * 8 + 4);
        float2 w1 = emb2[(size_t)ei1 * 256 + off2];
        float4 a1 = *(const float4*)(E0 + (size_t)ei1 * 32 + bg * 8);
        float4 b1 = *(const float4*)(E0 + (size_t)ei1 * 32 + bg * 8 + 4);
        G1_FMA(w0, a0, 0) G1_FMA(w0, b0, 4)
        G1_FMA(w1, a1, 0) G1_FMA(w1, b1, 4)
    }
    if (i < cnt) {
        int ei0 = LIST[i];
        float2 w0 = emb2[(size_t)ei0 * 256 + off2];
        float4 a0 = *(const float4*)(E0 + (size_t)ei0 * 32 + bg * 8);
        float4 b0 = *(const float4*)(E0 + (size_t)ei0 * 32 + bg * 8 + 4);
        G1_FMA(w0, a0, 0) G1_FMA(w0, b0, 4)
    }
#undef G1_FMA

    // plain store: block owns disjoint slice PPART[lc][bg*8..+8][dc*128..+128]
    float* pp = PPART + ((size_t)lc * 32 + bg * 8) * DH + dc * 128 + dl * 2;
    #pragma unroll
    for (int k = 0; k < 8; ++k) *(float2*)(pp + (size_t)k * DH) = acc[k];
}

// ---------------------------------------------------------------------------
// reduceP: P[j] = sum_lc PPART[lc][j]   (16384 floats = 4096 float4)
// ---------------------------------------------------------------------------
__global__ __launch_bounds__(256) void reduceP_kernel(
    const float* __restrict__ PPART, float* __restrict__ P)
{
    int j = blockIdx.x * 256 + threadIdx.x;     // float4 index, 4096 total
    const float4* pp = (const float4*)PPART;
    float4 s; s.x = s.y = s.z = s.w = 0.f;
    for (int lc = 0; lc < G1_LC; ++lc) {
        float4 v = pp[(size_t)lc * (B * DH / 4) + j];
        s.x += v.x; s.y += v.y; s.z += v.z; s.w += v.w;
    }
    ((float4*)P)[j] = s;
}

// ---------------------------------------------------------------------------
// gemm2: out1[b,e] = sum_d (P[b,d]/(S[b]+1e-6)) * emb[e,d] + bias[e]
// block: 512 entities (2 per thread); p staged+scaled in LDS (64 KB)
// ---------------------------------------------------------------------------
__global__ __launch_bounds__(256) void gemm2_kernel(
    const float* __restrict__ P, const float* __restrict__ S,
    const float* __restrict__ emb, const float* __restrict__ bias,
    float* __restrict__ out1)
{
    __shared__ float pl[B * DH];
    int tid = threadIdx.x;
    for (int k = tid; k < B * DH; k += 256) {
        int b = k >> 9;
        pl[k] = P[k] / (S[b] + 1e-6f);
    }
    __syncthreads();

    int base = blockIdx.x * 512;
    int e0 = base + tid, e1 = base + 256 + tid;
    int g0 = e0 < NE ? e0 : NE - 1;
    int g1 = e1 < NE ? e1 : NE - 1;
    const float4* emb4 = (const float4*)emb;
    const float4* pl4  = (const float4*)pl;

    float acc0[32], acc1[32];
    #pragma unroll
    for (int b = 0; b < 32; ++b) { acc0[b] = 0.f; acc1[b] = 0.f; }

    for (int dg = 0; dg < 128; ++dg) {
        float4 w0 = emb4[(size_t)g0 * 128 + dg];
        float4 w1 = emb4[(size_t)g1 * 128 + dg];
        #pragma unroll
        for (int b = 0; b < 32; ++b) {
            float4 pv = pl4[b * 128 + dg];      // broadcast
            acc0[b] += w0.x * pv.x + w0.y * pv.y + w0.z * pv.z + w0.w * pv.w;
            acc1[b] += w1.x * pv.x + w1.y * pv.y + w1.z * pv.z + w1.w * pv.w;
        }
    }
    float b0 = bias[g0], b1 = bias[g1];
    #pragma unroll
    for (int b = 0; b < 32; ++b) {
        if (e0 < NE) out1[(size_t)b * NE + e0] = acc0[b] + b0;
        if (e1 < NE) out1[(size_t)b * NE + e1] = acc1[b] + b1;
    }
}

// ---------------------------------------------------------------------------
extern "C" void kernel_launch(void* const* d_in, const int* in_sizes, int n_in,
                              void* d_out, int out_size, void* d_ws, size_t ws_size,
                              hipStream_t stream)
{
    const int*   questions = (const int*)d_in[0];
    const float* e_s       = (const float*)d_in[1];
    const float* answers   = (const float*)d_in[2];
    const int*   subj      = (const int*)d_in[3];
    const int*   rel       = (const int*)d_in[4];
    const int*   obj       = (const int*)d_in[5];
    const float* rel_emb   = (const float*)d_in[6];
    const float* step_W    = (const float*)d_in[7];
    const float* step_b    = (const float*)d_in[8];
    const float* ent_emb   = (const float*)d_in[9];
    const float* ent_bias  = (const float*)d_in[10];

    float* out0 = (float*)d_out;              // e_score (B,NE)
    float* out1 = out0 + (size_t)B * NE;      // pred_e  (B,NE)

    // workspace layout (~39 MB)
    float* w  = (float*)d_ws;
    float* E0 = w;
    float* E1 = E0 + (size_t)NE * B;
    float* E2 = E1 + (size_t)NE * B;          // dead after follow step 2 ->
                                              // reused as gemm1 partial buffer
    float* RD = E2 + (size_t)NE * B;          // rel_dist transposed (NR,B)
    float* P  = RD + NR * B;                  // (B,DH)
    float* S  = P + B * DH;                   // (B,)
    float* GT = S + B;                        // (B,)
    int* AM    = (int*)(GT + B);              // (3,B) argmaxes
    int* COND  = AM + 3 * B;                  // cond1 at COND, cond2 at COND+B
    int* FLAG3 = COND + 2 * B;                // (B,)
    int* SRC   = FLAG3 + B;                   // (B,)
    int* ANS   = SRC + B;                     // (B,)
    int* LIST  = ANS + B;                     // (<=NE) nonzero-entity list
    int* CNT   = LIST + NE;                   // (1,)
    float* PPART = E2;                        // G1_LC * 32 * 512 floats = 8 MB

    const int postGrid = NE * B / 256;        // 12500

    prep_kernel<<<NE / 32, 256, 0, stream>>>(e_s, answers, E0, E1, SRC, ANS);

    // --- step 0 ---
    stepA_kernel<<<B, 256, 0, stream>>>(0, questions, rel_emb, step_W, step_b,
                                        RD, GT, AM, COND, FLAG3);
    follow_kernel<<<NT * 32 / 256, 256, 0, stream>>>(E0, E1, RD, subj, rel, obj);
    post0_kernel<<<postGrid, 256, 0, stream>>>(E1, E2, ANS, GT);

    // --- step 1 ---
    stepA_kernel<<<B, 256, 0, stream>>>(1, questions, rel_emb, step_W, step_b,
                                        RD, GT, AM, COND, FLAG3);
    follow_kernel<<<NT * 32 / 256, 256, 0, stream>>>(E1, E2, RD, subj, rel, obj);
    post1_kernel<<<postGrid, 256, 0, stream>>>(E2, E0, COND, SRC, P, S, CNT);

    // --- step 2 ---
    stepA_kernel<<<B, 256, 0, stream>>>(2, questions, rel_emb, step_W, step_b,
                                        RD, GT, AM, COND, FLAG3);
    follow_kernel<<<NT * 32 / 256, 256, 0, stream>>>(E2, E0, RD, subj, rel, obj);
    post2_kernel<<<POST2_BLOCKS, 256, 0, stream>>>(E0, E1, COND + B, SRC, FLAG3,
                                                   S, LIST, CNT);

    // --- outputs ---
    outT_kernel<<<NE / 32, 256, 0, stream>>>(E0, out0);
    gemm1_kernel<<<G1_BLOCKS, 256, 0, stream>>>(E0, ent_emb, LIST, CNT, PPART);
    reduceP_kernel<<<B * DH / 4 / 256, 256, 0, stream>>>(PPART, P);
    gemm2_kernel<<<(NE + 511) / 512, 256, 0, stream>>>(P, S, ent_emb, ent_bias, out1);
}